// Round 2
// baseline (299.361 us; speedup 1.0000x reference)
//
#include <hip/hip_runtime.h>

static constexpr int T_LEN = 4096;          // time axis length
static constexpr int GROUPS = T_LEN / 256;  // 16 groups of 256 elems per wave-row
#define EPSV 1e-6f

typedef float vfloat4 __attribute__((ext_vector_type(4)));

// raw hw transcendentals: exp2/log2 (avoid libm-name collisions in -x hip mode)
__device__ __forceinline__ float fexp2(float x) { return __builtin_amdgcn_exp2f(x); }
__device__ __forceinline__ float flog2(float x) { return __builtin_amdgcn_logf(x); }

// order-preserving float<->uint transform (works for negatives too)
__device__ __forceinline__ unsigned int flip_f(float f) {
    unsigned int u = __float_as_uint(f);
    return u ^ ((u >> 31) ? 0xFFFFFFFFu : 0x80000000u);
}
__device__ __forceinline__ float unflip_f(unsigned int u) {
    u ^= ((u >> 31) ? 0x80000000u : 0xFFFFFFFFu);
    return __uint_as_float(u);
}

__global__ void init_ws(unsigned int* ws) {
    ws[0] = 0xFFFFFFFFu;  // min slot (transformed +max)
    ws[1] = 0x00000000u;  // max slot (transformed -max)
}

// PASS 0: compute pcen, reduce global min/max into ws.
// PASS 1: recompute pcen, normalize with ws min/max, store to out.
template <int PASS>
__launch_bounds__(256, 4)
__global__ void pcen_pass(const float* __restrict__ E,
                          const float* __restrict__ sp,
                          const float* __restrict__ ap,
                          const float* __restrict__ dp,
                          const float* __restrict__ rp,
                          float* __restrict__ out,
                          unsigned int* __restrict__ ws,
                          int rows)
{
    const int tid  = threadIdx.x;
    const int lane = tid & 63;
    const int wv   = tid >> 6;
    const int row  = blockIdx.x * 4 + wv;

    float s = sp[0];
    s = fminf(fmaxf(s, 0.0f), 1.0f);
    const float a     = 1.0f - s;
    const float alpha = ap[0];
    const float delta = dp[0];
    const float r     = rp[0];
    const float na    = -alpha;
    const float dr    = fexp2(r * flog2(delta));

    // powers of a for the lane scan (ratio per lane-chunk is a^4)
    const float a2 = a * a, a4 = a2 * a2, a8 = a4 * a4, a16 = a8 * a8,
                a32 = a16 * a16, a64 = a32 * a32, a128 = a64 * a64,
                a256 = a128 * a128;
    float pwl;  // a^(4*lane)
    if (a > 0.0f) pwl = fexp2((float)(4 * lane) * flog2(a));
    else          pwl = (lane == 0) ? 1.0f : 0.0f;

    float scale = 0.0f, bias = 0.0f;
    if (PASS == 1) {
        const float pmin = unflip_f(ws[0]);
        const float pmax = unflip_f(ws[1]);
        const float inv  = 2.0f / (pmax - pmin);
        scale = inv;
        bias  = __builtin_fmaf(-pmin, inv, -1.0f);
    }

    float vmin = __builtin_inff(), vmax = -__builtin_inff();

    if (row < rows) {
        const float4* __restrict__ src = (const float4*)(E + (size_t)row * T_LEN);
        float* __restrict__ drow = out + (size_t)row * T_LEN;

        // seed: since a+s==1, carry=E[0] makes uniform recurrence yield M[0]=E[0]
        float carry = E[(size_t)row * T_LEN];
        float4 cur = src[lane];

        for (int g = 0; g < GROUPS; ++g) {
            float4 nxt = make_float4(0.f, 0.f, 0.f, 0.f);
            if (g + 1 < GROUPS) nxt = src[(g + 1) * 64 + lane];  // prefetch

            // local weighted sum over this lane's 4 elements (Horner)
            float b = cur.x;
            b = __builtin_fmaf(a, b, cur.y);
            b = __builtin_fmaf(a, b, cur.z);
            b = __builtin_fmaf(a, b, cur.w);
            float B = s * b;

            // inclusive wave scan: B_i += a^(4k) * B_{i-k}
            float t;
            t = __shfl_up(B, 1, 64);  if (lane >= 1)  B = __builtin_fmaf(a4,   t, B);
            t = __shfl_up(B, 2, 64);  if (lane >= 2)  B = __builtin_fmaf(a8,   t, B);
            t = __shfl_up(B, 4, 64);  if (lane >= 4)  B = __builtin_fmaf(a16,  t, B);
            t = __shfl_up(B, 8, 64);  if (lane >= 8)  B = __builtin_fmaf(a32,  t, B);
            t = __shfl_up(B, 16, 64); if (lane >= 16) B = __builtin_fmaf(a64,  t, B);
            t = __shfl_up(B, 32, 64); if (lane >= 32) B = __builtin_fmaf(a128, t, B);

            float Bex = __shfl_up(B, 1, 64);
            if (lane == 0) Bex = 0.0f;
            const float B63 = __shfl(B, 63, 64);

            float m = __builtin_fmaf(pwl, carry, Bex);   // M just before this lane's chunk
            carry   = __builtin_fmaf(a256, carry, B63);  // M at end of group

            float4 o;
            float p;
            m = __builtin_fmaf(a, m, s * cur.x);
            p = fexp2(r * flog2(__builtin_fmaf(cur.x, fexp2(na * flog2(EPSV + m)), delta))) - dr;
            if (PASS == 0) { vmin = fminf(vmin, p); vmax = fmaxf(vmax, p); }
            else            o.x = __builtin_fmaf(p, scale, bias);

            m = __builtin_fmaf(a, m, s * cur.y);
            p = fexp2(r * flog2(__builtin_fmaf(cur.y, fexp2(na * flog2(EPSV + m)), delta))) - dr;
            if (PASS == 0) { vmin = fminf(vmin, p); vmax = fmaxf(vmax, p); }
            else            o.y = __builtin_fmaf(p, scale, bias);

            m = __builtin_fmaf(a, m, s * cur.z);
            p = fexp2(r * flog2(__builtin_fmaf(cur.z, fexp2(na * flog2(EPSV + m)), delta))) - dr;
            if (PASS == 0) { vmin = fminf(vmin, p); vmax = fmaxf(vmax, p); }
            else            o.z = __builtin_fmaf(p, scale, bias);

            m = __builtin_fmaf(a, m, s * cur.w);
            p = fexp2(r * flog2(__builtin_fmaf(cur.w, fexp2(na * flog2(EPSV + m)), delta))) - dr;
            if (PASS == 0) { vmin = fminf(vmin, p); vmax = fmaxf(vmax, p); }
            else            o.w = __builtin_fmaf(p, scale, bias);

            if (PASS == 1) {
                // non-temporal store: keep E resident in L3 for reuse
                vfloat4 ov = { o.x, o.y, o.z, o.w };
                __builtin_nontemporal_store(ov, (vfloat4*)(drow + (size_t)(g * 64 + lane) * 4));
            }
            cur = nxt;
        }
    }

    if (PASS == 0) {
        // wave reduce
        for (int off = 32; off >= 1; off >>= 1) {
            vmin = fminf(vmin, __shfl_xor(vmin, off, 64));
            vmax = fmaxf(vmax, __shfl_xor(vmax, off, 64));
        }
        __shared__ unsigned int smin, smax;
        if (tid == 0) { smin = 0xFFFFFFFFu; smax = 0u; }
        __syncthreads();
        if (lane == 0 && row < rows) {
            atomicMin(&smin, flip_f(vmin));
            atomicMax(&smax, flip_f(vmax));
        }
        __syncthreads();
        if (tid == 0) {
            atomicMin(&ws[0], smin);
            atomicMax(&ws[1], smax);
        }
    }
}

extern "C" void kernel_launch(void* const* d_in, const int* in_sizes, int n_in,
                              void* d_out, int out_size, void* d_ws, size_t ws_size,
                              hipStream_t stream) {
    const float* E     = (const float*)d_in[0];
    const float* s     = (const float*)d_in[1];
    const float* alpha = (const float*)d_in[2];
    const float* delta = (const float*)d_in[3];
    const float* r     = (const float*)d_in[4];
    float* out         = (float*)d_out;
    unsigned int* ws   = (unsigned int*)d_ws;

    const int rows   = in_sizes[0] / T_LEN;   // 8192 for (32,256,4096)
    const int blocks = (rows + 3) / 4;        // 4 rows (waves) per 256-thread block

    hipLaunchKernelGGL(init_ws, dim3(1), dim3(1), 0, stream, ws);
    hipLaunchKernelGGL((pcen_pass<0>), dim3(blocks), dim3(256), 0, stream,
                       E, s, alpha, delta, r, out, ws, rows);
    hipLaunchKernelGGL((pcen_pass<1>), dim3(blocks), dim3(256), 0, stream,
                       E, s, alpha, delta, r, out, ws, rows);
}